// Round 1
// baseline (242.324 us; speedup 1.0000x reference)
//
#include <hip/hip_runtime.h>
#include <cstdint>
#include <cstddef>

// Problem constants (from reference setup_inputs)
#define C_ 4
#define B_ 128
#define G_ 2048
#define S_ 32
#define L_ 3
#define NSTEP_ 3
#define GAMMA_ 0.01f
#define INVG_ 100.0f
#define NG_ 4  // (c,g) pairs per gather block

// ---------------------------------------------------------------------------
// k_init: A[c,g,b] = x[b,g]  (transpose + broadcast over clauses)
// block (32,8), grid (G/32, B/32, C). LDS-tiled to keep both sides coalesced.
// ---------------------------------------------------------------------------
__global__ __launch_bounds__(256) void k_init(const float* __restrict__ x,
                                              float* __restrict__ A) {
  __shared__ float tile[32][33];
  const int g0 = blockIdx.x * 32, b0 = blockIdx.y * 32, c = blockIdx.z;
  const int tx = threadIdx.x;
  for (int i = threadIdx.y; i < 32; i += 8)
    tile[i][tx] = x[(size_t)(b0 + i) * G_ + g0 + tx];  // tile[b-b0][g-g0]
  __syncthreads();
  for (int j = threadIdx.y; j < 32; j += 8)
    A[((size_t)c * G_ + g0 + j) * B_ + b0 + tx] = tile[tx][j];
}

// ---------------------------------------------------------------------------
// k_gather: per (c,g): body[s] = prod_l A[c, I[c,g,s,l], b] * scale, then
// lse1 = gamma*logsumexp(body/gamma) over s. Writes lse1 to Lout[c,g,b],
// atomicMax's the global max into slots[out_slot].
// scale = previous step's lazy normalization (1/m2_prev if >1).
// 128 threads = b lanes; indices are wave-uniform via LDS broadcast.
// ---------------------------------------------------------------------------
__global__ __launch_bounds__(128) void k_gather(const float* __restrict__ A,
                                                const int* __restrict__ Idx,
                                                float* __restrict__ Lout,
                                                uint32_t* __restrict__ slots,
                                                int prev_slot, int out_slot) {
  __shared__ int sidx[S_ * L_];
  __shared__ uint32_t smax;
  const int tid = threadIdx.x;
  if (tid == 0) smax = 0u;
  const float mprev = __uint_as_float(slots[prev_slot]);
  const float scale = (mprev > 1.0f) ? (1.0f / mprev) : 1.0f;
  float tmax = 0.0f;

  for (int q = 0; q < NG_; ++q) {
    const int cg = blockIdx.x * NG_ + q;
    const int c = cg >> 11;  // / G_
    __syncthreads();  // protect sidx reuse
    if (tid < S_ * L_) sidx[tid] = Idx[(size_t)cg * (S_ * L_) + tid];
    __syncthreads();

    const float* Ac = A + (size_t)c * G_ * B_ + tid;
    float body[S_];
#pragma unroll
    for (int s = 0; s < S_; ++s) {
      float v0 = Ac[(size_t)sidx[3 * s + 0] * B_];
      float v1 = Ac[(size_t)sidx[3 * s + 1] * B_];
      float v2 = Ac[(size_t)sidx[3 * s + 2] * B_];
      body[s] = (v0 * scale) * (v1 * scale) * (v2 * scale);
    }
    float m = body[0];
#pragma unroll
    for (int s = 1; s < S_; ++s) m = fmaxf(m, body[s]);
    float acc = 0.0f;
#pragma unroll
    for (int s = 0; s < S_; ++s) acc += __expf((body[s] - m) * INVG_);
    const float lse = m + GAMMA_ * __logf(acc);
    Lout[(size_t)cg * B_ + tid] = lse;
    tmax = fmaxf(tmax, lse);
  }
  // values are strictly positive -> uint bit compare == float compare
  atomicMax(&smax, __float_as_uint(tmax));
  __syncthreads();
  if (tid == 0) atomicMax(slots + out_slot, smax);
}

// ---------------------------------------------------------------------------
// k_elem: R = A*sprev (prev step's pending scale); ce = lse1*s1 (m1 norm);
// A = gamma*logsumexp([R,ce]/gamma) over the 2-stack; atomicMax global max.
// ---------------------------------------------------------------------------
__global__ __launch_bounds__(256) void k_elem(float* __restrict__ A,
                                              const float* __restrict__ Lin,
                                              uint32_t* __restrict__ slots,
                                              int prev_slot, int m1_slot,
                                              int out_slot) {
  __shared__ uint32_t smax;
  if (threadIdx.x == 0) smax = 0u;
  __syncthreads();
  const float mprev = __uint_as_float(slots[prev_slot]);
  const float sprev = (mprev > 1.0f) ? (1.0f / mprev) : 1.0f;
  const float m1 = __uint_as_float(slots[m1_slot]);
  const float s1 = (m1 > 1.0f) ? (1.0f / m1) : 1.0f;
  float tmax = 0.0f;
  const size_t total = (size_t)C_ * G_ * B_;
  const size_t stride = (size_t)gridDim.x * blockDim.x;
  for (size_t i = (size_t)blockIdx.x * blockDim.x + threadIdx.x; i < total;
       i += stride) {
    const float R = A[i] * sprev;
    const float ce = Lin[i] * s1;
    const float M = fmaxf(R, ce);
    const float mn = fminf(R, ce);
    // 2-elem logsumexp: M + gamma*log(1 + exp((mn-M)/gamma))
    const float lse2 = M + GAMMA_ * __logf(1.0f + __expf((mn - M) * INVG_));
    A[i] = lse2;
    tmax = fmaxf(tmax, lse2);
  }
  atomicMax(&smax, __float_as_uint(tmax));
  __syncthreads();
  if (threadIdx.x == 0) atomicMax(slots + out_slot, smax);
}

// ---------------------------------------------------------------------------
// k_out: out[c,b,g] = A[c,g,b] * final_scale  (LDS-tiled transpose back)
// ---------------------------------------------------------------------------
__global__ __launch_bounds__(256) void k_out(const float* __restrict__ A,
                                             float* __restrict__ out,
                                             const uint32_t* __restrict__ slots,
                                             int mslot) {
  __shared__ float tile[32][33];
  const float mfin = __uint_as_float(slots[mslot]);
  const float sc = (mfin > 1.0f) ? (1.0f / mfin) : 1.0f;
  const int g0 = blockIdx.x * 32, b0 = blockIdx.y * 32, c = blockIdx.z;
  const int tx = threadIdx.x;
  for (int j = threadIdx.y; j < 32; j += 8)
    tile[j][tx] = A[((size_t)c * G_ + g0 + j) * B_ + b0 + tx];  // tile[g][b]
  __syncthreads();
  for (int i = threadIdx.y; i < 32; i += 8)
    out[((size_t)c * B_ + b0 + i) * G_ + g0 + tx] = tile[tx][i] * sc;
}

extern "C" void kernel_launch(void* const* d_in, const int* in_sizes, int n_in,
                              void* d_out, int out_size, void* d_ws,
                              size_t ws_size, hipStream_t stream) {
  const float* x = (const float*)d_in[0];  // [B,G]
  const int* Idx = (const int*)d_in[1];    // [C,G,S,L]
  float* out = (float*)d_out;              // [C,B,G]

  char* ws = (char*)d_ws;
  uint32_t* slots = (uint32_t*)ws;  // 8 scalar max slots
  float* A = (float*)(ws + 256);                                  // [C,G,B] 4MB
  float* Lb = (float*)(ws + 256 + (size_t)C_ * G_ * B_ * 4);      // [C,G,B] 4MB

  hipMemsetAsync(slots, 0, 8 * sizeof(uint32_t), stream);

  dim3 tb(32, 8);
  k_init<<<dim3(G_ / 32, B_ / 32, C_), tb, 0, stream>>>(x, A);

  for (int step = 0; step < NSTEP_; ++step) {
    const int prev = 2 * step;      // m2 of previous step (slot 0 == 0 -> scale 1)
    const int m1s = 2 * step + 1;
    const int m2s = 2 * step + 2;
    k_gather<<<(C_ * G_) / NG_, 128, 0, stream>>>(A, Idx, Lb, slots, prev, m1s);
    k_elem<<<1024, 256, 0, stream>>>(A, Lb, slots, prev, m1s, m2s);
  }

  k_out<<<dim3(G_ / 32, B_ / 32, C_), tb, 0, stream>>>(A, out, slots,
                                                       2 * NSTEP_);
}